// Round 2
// baseline (33155.786 us; speedup 1.0000x reference)
//
#include <hip/hip_runtime.h>
#include <hip/hip_bf16.h>
#include <math.h>

// Problem constants
#define A_DIM 1024      // NB_ATOMS
#define D_DIM 768       // 3*16*16
#define B_DIM 16384     // BATCH
#define TEMP_C 100.0f
#define EPS_C 1e-8f

// Layout: everything "transposed" vs the reference: [B, A] row-major.
//   Gt = Ct @ X - qt   (X symmetric => equals (X@c - q)^T)
// Workspace budget: only 3 big [B,A] buffers (Ct, Gt, qt) ~= 199 MiB total.
// XD / Dt buffers are eliminated algebraically:
//   nondiff: denom = pairsum(X | bstar equal) - 2*sum_b am.(Xc) + sum_b c.(Xc),
//            with Xc = Gt + qt  (no X@d GEMM at all)
//   diff:    sm overwrites Gt; denom's sm.(X@sm) term via a reduce-only GEMM
//            (tile stays in registers, atomicAdd scalar, nothing stored)

// ---------------- small helpers ----------------

__device__ __forceinline__ float block_reduce_sum(float v, float* red) {
    int t = threadIdx.x;
    red[t] = v; __syncthreads();
    for (int off = 128; off > 0; off >>= 1) {
        if (t < off) red[t] += red[t + off];
        __syncthreads();
    }
    float r = red[0];
    __syncthreads();
    return r;
}

__device__ __forceinline__ float block_reduce_max(float v, float* red) {
    int t = threadIdx.x;
    red[t] = v; __syncthreads();
    for (int off = 128; off > 0; off >>= 1) {
        if (t < off) red[t] = fmaxf(red[t], red[t + off]);
        __syncthreads();
    }
    float r = red[0];
    __syncthreads();
    return r;
}

// monotone float->uint transform for ordered integer min
__device__ __forceinline__ unsigned int fkey(float v) {
    unsigned int u = __float_as_uint(v);
    return u ^ ((u & 0x80000000u) ? 0xFFFFFFFFu : 0x80000000u);
}

// ---------------- setup kernels ----------------

__global__ __launch_bounds__(256) void ynorm_kernel(const float* __restrict__ y,
                                                    float* __restrict__ ynorm) {
    __shared__ float red[256];
    int b = blockIdx.x;
    const float* row = y + (size_t)b * D_DIM;
    float s = 0.f;
    for (int i = threadIdx.x; i < D_DIM; i += 256) s += fabsf(row[i]);
    float tot = block_reduce_sum(s, red);
    if (threadIdx.x == 0) ynorm[b] = tot;
}

__global__ __launch_bounds__(256) void anorm_kernel(const float* __restrict__ atoms,
                                                    float* __restrict__ an) {
    __shared__ float red[256];
    int a = blockIdx.x;
    const float* row = atoms + (size_t)a * D_DIM;
    float s = 0.f;
    for (int i = threadIdx.x; i < D_DIM; i += 256) s += fabsf(row[i]);
    float tot = block_reduce_sum(s, red);
    float inv = 1.f / tot;
    float* orow = an + (size_t)a * D_DIM;
    for (int i = threadIdx.x; i < D_DIM; i += 256) orow[i] = row[i] * inv;
}

__global__ __launch_bounds__(256) void fill_kernel(float* __restrict__ p, float v, size_t n4) {
    size_t i = (size_t)blockIdx.x * 256 + threadIdx.x;
    if (i < n4) ((float4*)p)[i] = make_float4(v, v, v, v);
}

// ---------------- GEMM: C[M,N] = A[M,K] * B, 128x128x16 tiles ----------------
// BT=false: B stored [K,N] row-major.  BT=true: B stored [N,K] row-major.
// EPI: 0 = plain, 1 = subtract Qsub[row,col], 2 = *rscale[row], 3 = /rscale[row]
template <bool BT, int EPI>
__global__ __launch_bounds__(256) void gemm_k(const float* __restrict__ Aop,
                                              const float* __restrict__ Bop,
                                              const float* __restrict__ Qsub,
                                              const float* __restrict__ rscale,
                                              float* __restrict__ Cout,
                                              int M, int N, int K) {
    const int LDT = 132;
    __shared__ float As[16 * LDT];
    __shared__ float Bs[16 * LDT];
    int m0 = blockIdx.y * 128, n0 = blockIdx.x * 128;
    int tid = threadIdx.x;
    int tx = tid & 15, ty = tid >> 4;

    float acc[8][8];
#pragma unroll
    for (int i = 0; i < 8; i++)
#pragma unroll
        for (int j = 0; j < 8; j++) acc[i][j] = 0.f;

    for (int k0 = 0; k0 < K; k0 += 16) {
#pragma unroll
        for (int s = 0; s < 2; s++) {
            int idx = tid + s * 256;
            int row = idx >> 2, kq = (idx & 3) * 4;
            float4 v = *(const float4*)(Aop + (size_t)(m0 + row) * K + k0 + kq);
            As[(kq + 0) * LDT + row] = v.x;
            As[(kq + 1) * LDT + row] = v.y;
            As[(kq + 2) * LDT + row] = v.z;
            As[(kq + 3) * LDT + row] = v.w;
        }
        if (BT) {
#pragma unroll
            for (int s = 0; s < 2; s++) {
                int idx = tid + s * 256;
                int row = idx >> 2, kq = (idx & 3) * 4;
                float4 v = *(const float4*)(Bop + (size_t)(n0 + row) * K + k0 + kq);
                Bs[(kq + 0) * LDT + row] = v.x;
                Bs[(kq + 1) * LDT + row] = v.y;
                Bs[(kq + 2) * LDT + row] = v.z;
                Bs[(kq + 3) * LDT + row] = v.w;
            }
        } else {
#pragma unroll
            for (int s = 0; s < 2; s++) {
                int idx = tid + s * 256;
                int kr = idx >> 5, nq = (idx & 31) * 4;
                float4 v = *(const float4*)(Bop + (size_t)(k0 + kr) * N + n0 + nq);
                *(float4*)(Bs + kr * LDT + nq) = v;
            }
        }
        __syncthreads();
#pragma unroll
        for (int kk = 0; kk < 16; kk++) {
            float a[8], b[8];
            *(float4*)(a)     = *(const float4*)(As + kk * LDT + ty * 8);
            *(float4*)(a + 4) = *(const float4*)(As + kk * LDT + ty * 8 + 4);
            *(float4*)(b)     = *(const float4*)(Bs + kk * LDT + tx * 8);
            *(float4*)(b + 4) = *(const float4*)(Bs + kk * LDT + tx * 8 + 4);
#pragma unroll
            for (int i = 0; i < 8; i++)
#pragma unroll
                for (int j = 0; j < 8; j++) acc[i][j] = fmaf(a[i], b[j], acc[i][j]);
        }
        __syncthreads();
    }

#pragma unroll
    for (int i = 0; i < 8; i++) {
        int row = m0 + ty * 8 + i;
        float rs = 1.f;
        if (EPI == 2) rs = rscale[row];
        if (EPI == 3) rs = 1.f / rscale[row];
#pragma unroll
        for (int j = 0; j < 8; j += 4) {
            int col = n0 + tx * 8 + j;
            float4 v = make_float4(acc[i][j], acc[i][j + 1], acc[i][j + 2], acc[i][j + 3]);
            if (EPI == 1) {
                float4 q = *(const float4*)(Qsub + (size_t)row * N + col);
                v.x -= q.x; v.y -= q.y; v.z -= q.z; v.w -= q.w;
            } else if (EPI == 2 || EPI == 3) {
                v.x *= rs; v.y *= rs; v.z *= rs; v.w *= rs;
            }
            *(float4*)(Cout + (size_t)row * N + col) = v;
        }
    }
}

// Reduce-only GEMM for the diff-step denominator: T = Sm@X tile in registers,
// partial = sum(T .* Sm_tile), atomicAdd(denom, partial). Stores nothing.
__global__ __launch_bounds__(256) void gemm_dot_kernel(const float* __restrict__ Sm,
                                                       const float* __restrict__ X,
                                                       float* __restrict__ denom) {
    const int LDT = 132;
    __shared__ float As[16 * LDT];
    __shared__ float Bs[16 * LDT];
    __shared__ float red[256];
    const int N = A_DIM, K = A_DIM;
    int m0 = blockIdx.y * 128, n0 = blockIdx.x * 128;
    int tid = threadIdx.x;
    int tx = tid & 15, ty = tid >> 4;

    float acc[8][8];
#pragma unroll
    for (int i = 0; i < 8; i++)
#pragma unroll
        for (int j = 0; j < 8; j++) acc[i][j] = 0.f;

    for (int k0 = 0; k0 < K; k0 += 16) {
#pragma unroll
        for (int s = 0; s < 2; s++) {
            int idx = tid + s * 256;
            int row = idx >> 2, kq = (idx & 3) * 4;
            float4 v = *(const float4*)(Sm + (size_t)(m0 + row) * K + k0 + kq);
            As[(kq + 0) * LDT + row] = v.x;
            As[(kq + 1) * LDT + row] = v.y;
            As[(kq + 2) * LDT + row] = v.z;
            As[(kq + 3) * LDT + row] = v.w;
        }
#pragma unroll
        for (int s = 0; s < 2; s++) {
            int idx = tid + s * 256;
            int kr = idx >> 5, nq = (idx & 31) * 4;
            float4 v = *(const float4*)(X + (size_t)(k0 + kr) * N + n0 + nq);
            *(float4*)(Bs + kr * LDT + nq) = v;
        }
        __syncthreads();
#pragma unroll
        for (int kk = 0; kk < 16; kk++) {
            float a[8], b[8];
            *(float4*)(a)     = *(const float4*)(As + kk * LDT + ty * 8);
            *(float4*)(a + 4) = *(const float4*)(As + kk * LDT + ty * 8 + 4);
            *(float4*)(b)     = *(const float4*)(Bs + kk * LDT + tx * 8);
            *(float4*)(b + 4) = *(const float4*)(Bs + kk * LDT + tx * 8 + 4);
#pragma unroll
            for (int i = 0; i < 8; i++)
#pragma unroll
                for (int j = 0; j < 8; j++) acc[i][j] = fmaf(a[i], b[j], acc[i][j]);
        }
        __syncthreads();
    }

    float part = 0.f;
#pragma unroll
    for (int i = 0; i < 8; i++) {
        int row = m0 + ty * 8 + i;
#pragma unroll
        for (int j = 0; j < 8; j += 4) {
            int col = n0 + tx * 8 + j;
            float4 s = *(const float4*)(Sm + (size_t)row * A_DIM + col);
            part += acc[i][j] * s.x + acc[i][j + 1] * s.y + acc[i][j + 2] * s.z + acc[i][j + 3] * s.w;
        }
    }
    float tot = block_reduce_sum(part, red);
    if (tid == 0) atomicAdd(denom, tot);
}

// ---------------- per-iteration kernels ----------------

__global__ __launch_bounds__(256) void init_iter_kernel(unsigned long long* __restrict__ keys,
                                                        float* __restrict__ denom) {
    int t = blockIdx.x * 256 + threadIdx.x;
    if (t < A_DIM) keys[t] = 0xFFFFFFFFFFFFFFFFULL;
    if (t == 0) *denom = 0.f;
}

// argmin over rows (samples) for each column (atom) of Gt[B,A]
__global__ __launch_bounds__(256) void argmin_kernel(const float* __restrict__ Gt,
                                                     unsigned long long* __restrict__ keys) {
    __shared__ unsigned long long sk[256];
    int a0 = blockIdx.x * 64;
    int b0 = blockIdx.y * 1024;
    int c = threadIdx.x & 63;
    int r = threadIdx.x >> 6;
    float bestv = INFINITY;
    int bestb = 0;
    for (int b = b0 + r; b < b0 + 1024; b += 4) {
        float v = Gt[(size_t)b * A_DIM + a0 + c];
        if (v < bestv) { bestv = v; bestb = b; }  // strict < => first occurrence
    }
    unsigned long long key = ((unsigned long long)fkey(bestv) << 32) | (unsigned int)bestb;
    sk[threadIdx.x] = key;
    __syncthreads();
    if (r == 0) {
        unsigned long long k = sk[c];
        k = min(k, sk[64 + c]);
        k = min(k, sk[128 + c]);
        k = min(k, sk[192 + c]);
        atomicMin(&keys[a0 + c], k);
    }
}

__global__ __launch_bounds__(256) void extract_kernel(const unsigned long long* __restrict__ keys,
                                                      int* __restrict__ bstar) {
    int t = blockIdx.x * 256 + threadIdx.x;
    if (t < A_DIM) bstar[t] = (int)(unsigned int)(keys[t] & 0xFFFFFFFFULL);
}

// denom += sum over ordered pairs (a,a') with bstar[a]==bstar[a'] of X[a,a']
// (this is sum_b am_b^T X am_b). One block per a-row of X.
__global__ __launch_bounds__(256) void pairs_kernel(const float* __restrict__ X,
                                                    const int* __restrict__ bstar,
                                                    float* __restrict__ denom) {
    __shared__ float red[256];
    int a = blockIdx.x;
    int ba = bstar[a];
    const float* xr = X + (size_t)a * A_DIM;
    float s = 0.f;
    for (int i = threadIdx.x; i < A_DIM; i += 256)
        if (bstar[i] == ba) s += xr[i];
    float tot = block_reduce_sum(s, red);
    if (threadIdx.x == 0) atomicAdd(denom, tot);
}

// per row b (using Xc = Gt + qt):
//   num[b]  = c.g - am.g
//   denom  += c.(Xc) - 2*am.(Xc)      (pairs_kernel supplies the am.Xam term)
__global__ __launch_bounds__(256) void ndreduce_kernel(const float* __restrict__ Gt,
                                                       const float* __restrict__ qt,
                                                       const float* __restrict__ Ct,
                                                       const int* __restrict__ bstar,
                                                       float* __restrict__ num,
                                                       float* __restrict__ denom) {
    __shared__ float red[256];
    int b = blockIdx.x;
    int i = threadIdx.x;  // exactly 256 float4 per row
    float4 g = ((const float4*)(Gt + (size_t)b * A_DIM))[i];
    float4 q = ((const float4*)(qt + (size_t)b * A_DIM))[i];
    float4 c = ((const float4*)(Ct + (size_t)b * A_DIM))[i];
    int4 bs = ((const int4*)bstar)[i];
    float x0 = g.x + q.x, x1 = g.y + q.y, x2 = g.z + q.z, x3 = g.w + q.w;
    float a0 = (bs.x == b) ? 1.f : 0.f;
    float a1 = (bs.y == b) ? 1.f : 0.f;
    float a2 = (bs.z == b) ? 1.f : 0.f;
    float a3 = (bs.w == b) ? 1.f : 0.f;
    // num partial: c.g - am.g
    float np = (c.x - a0) * g.x + (c.y - a1) * g.y + (c.z - a2) * g.z + (c.w - a3) * g.w;
    // denom partial: (c - 2*am).(Xc)
    float dp = (c.x - 2.f * a0) * x0 + (c.y - 2.f * a1) * x1 + (c.z - 2.f * a2) * x2 + (c.w - 2.f * a3) * x3;
    float nt = block_reduce_sum(np, red);
    float dt = block_reduce_sum(dp, red);
    if (threadIdx.x == 0) {
        num[b] = nt;
        atomicAdd(denom, dt);
    }
}

__global__ __launch_bounds__(256) void ndupdate_kernel(float* __restrict__ Ct,
                                                       const int* __restrict__ bstar,
                                                       const float* __restrict__ num,
                                                       const float* __restrict__ denom) {
    int b = blockIdx.x;
    float den = *denom + EPS_C;
    float lam = num[b] / den;
    lam = fminf(fmaxf(lam, 0.f), 1.f);
    int i = threadIdx.x;
    float4* c4 = (float4*)(Ct + (size_t)b * A_DIM);
    const int4* bs4 = (const int4*)bstar;
    float4 c = c4[i];
    int4 bs = bs4[i];
    c.x += (((bs.x == b) ? 1.f : 0.f) - c.x) * lam;
    c.y += (((bs.y == b) ? 1.f : 0.f) - c.y) * lam;
    c.z += (((bs.z == b) ? 1.f : 0.f) - c.z) * lam;
    c.w += (((bs.w == b) ? 1.f : 0.f) - c.w) * lam;
    c4[i] = c;
}

// diff step: softmax over atoms per row; writes sm IN-PLACE into Gt;
//   num[b]  = -(sm - c).g
//   denom  += c.(Xc) - 2*sm.(Xc)     (gemm_dot supplies sm.(X@sm))
__global__ __launch_bounds__(256) void softmax_kernel(float* __restrict__ Gt,
                                                      const float* __restrict__ qt,
                                                      const float* __restrict__ Ct,
                                                      float* __restrict__ num,
                                                      float* __restrict__ denom) {
    __shared__ float red[256];
    int b = blockIdx.x;
    int i = threadIdx.x;
    float4* g4 = (float4*)(Gt + (size_t)b * A_DIM);
    float4 g = g4[i];
    float4 q = ((const float4*)(qt + (size_t)b * A_DIM))[i];
    float4 c = ((const float4*)(Ct + (size_t)b * A_DIM))[i];
    float4 l = make_float4(-TEMP_C * g.x, -TEMP_C * g.y, -TEMP_C * g.z, -TEMP_C * g.w);
    float m = fmaxf(fmaxf(l.x, l.y), fmaxf(l.z, l.w));
    float M = block_reduce_max(m, red);
    float4 e = make_float4(expf(l.x - M), expf(l.y - M), expf(l.z - M), expf(l.w - M));
    float S = block_reduce_sum(e.x + e.y + e.z + e.w, red);
    float inv = 1.f / S;
    float4 sm = make_float4(e.x * inv, e.y * inv, e.z * inv, e.w * inv);
    float np = (c.x - sm.x) * g.x + (c.y - sm.y) * g.y + (c.z - sm.z) * g.z + (c.w - sm.w) * g.w;
    float x0 = g.x + q.x, x1 = g.y + q.y, x2 = g.z + q.z, x3 = g.w + q.w;
    float dp = (c.x - 2.f * sm.x) * x0 + (c.y - 2.f * sm.y) * x1 +
               (c.z - 2.f * sm.z) * x2 + (c.w - 2.f * sm.w) * x3;
    g4[i] = sm;  // overwrite Gt row with softmax
    float nt = block_reduce_sum(np, red);
    float dt = block_reduce_sum(dp, red);
    if (threadIdx.x == 0) {
        num[b] = nt;
        atomicAdd(denom, dt);
    }
}

// Ct += (sm - Ct)*lam, with sm living in Gt
__global__ __launch_bounds__(256) void dupdate_kernel(float* __restrict__ Ct,
                                                      const float* __restrict__ Gt,
                                                      const float* __restrict__ num,
                                                      const float* __restrict__ denom) {
    int b = blockIdx.x;
    float den = *denom + EPS_C;
    float lam = num[b] / den;
    lam = fminf(fmaxf(lam, 0.f), 1.f);
    int i = threadIdx.x;
    float4* c4 = (float4*)(Ct + (size_t)b * A_DIM);
    const float4* s4 = (const float4*)(Gt + (size_t)b * A_DIM);
    float4 c = c4[i];
    float4 s = s4[i];
    c.x += (s.x - c.x) * lam;
    c.y += (s.y - c.y) * lam;
    c.z += (s.z - c.z) * lam;
    c.w += (s.w - c.w) * lam;
    c4[i] = c;
}

// ---------------- host launch ----------------

extern "C" void kernel_launch(void* const* d_in, const int* in_sizes, int n_in,
                              void* d_out, int out_size, void* d_ws, size_t ws_size,
                              hipStream_t stream) {
    const float* y = (const float*)d_in[0];      // [B, 768]
    const float* atoms = (const float*)d_in[1];  // [A, 768]
    float* out = (float*)d_out;                  // [B, 768]

    char* ws = (char*)d_ws;
    size_t off = 0;
    auto alloc = [&](size_t bytes) -> void* {
        void* p = ws + off;
        off += (bytes + 255) & ~(size_t)255;
        return p;
    };
    const size_t BA = (size_t)B_DIM * A_DIM;
    float* Ct = (float*)alloc(BA * 4);                       // 64 MiB
    float* Gt = (float*)alloc(BA * 4);                       // 64 MiB
    float* qt = (float*)alloc(BA * 4);                       // 64 MiB
    float* an = (float*)alloc((size_t)A_DIM * D_DIM * 4);    // 3 MiB
    float* X  = (float*)alloc((size_t)A_DIM * A_DIM * 4);    // 4 MiB
    float* ynorm = (float*)alloc(B_DIM * 4);
    float* num   = (float*)alloc(B_DIM * 4);
    unsigned long long* keys = (unsigned long long*)alloc(A_DIM * 8);
    int* bstar = (int*)alloc(A_DIM * 4);
    float* denom = (float*)alloc(256);
    (void)ws_size; (void)in_sizes; (void)n_in; (void)out_size;

    const int n4blocks = (int)(BA / 4 / 256);  // 16384

    // setup
    ynorm_kernel<<<B_DIM, 256, 0, stream>>>(y, ynorm);
    anorm_kernel<<<A_DIM, 256, 0, stream>>>(atoms, an);
    gemm_k<true, 0><<<dim3(A_DIM / 128, A_DIM / 128), 256, 0, stream>>>(
        an, an, nullptr, nullptr, X, A_DIM, A_DIM, D_DIM);
    gemm_k<true, 3><<<dim3(A_DIM / 128, B_DIM / 128), 256, 0, stream>>>(
        y, an, nullptr, ynorm, qt, B_DIM, A_DIM, D_DIM);
    fill_kernel<<<n4blocks, 256, 0, stream>>>(Ct, 1.f / A_DIM, BA / 4);

    // 30 nondiff steps
    for (int it = 0; it < 30; it++) {
        init_iter_kernel<<<4, 256, 0, stream>>>(keys, denom);
        gemm_k<false, 1><<<dim3(A_DIM / 128, B_DIM / 128), 256, 0, stream>>>(
            Ct, X, qt, nullptr, Gt, B_DIM, A_DIM, A_DIM);
        argmin_kernel<<<dim3(A_DIM / 64, B_DIM / 1024), 256, 0, stream>>>(Gt, keys);
        extract_kernel<<<4, 256, 0, stream>>>(keys, bstar);
        pairs_kernel<<<A_DIM, 256, 0, stream>>>(X, bstar, denom);
        ndreduce_kernel<<<B_DIM, 256, 0, stream>>>(Gt, qt, Ct, bstar, num, denom);
        ndupdate_kernel<<<B_DIM, 256, 0, stream>>>(Ct, bstar, num, denom);
    }

    // 10 diff steps
    for (int it = 0; it < 10; it++) {
        init_iter_kernel<<<4, 256, 0, stream>>>(keys, denom);
        gemm_k<false, 1><<<dim3(A_DIM / 128, B_DIM / 128), 256, 0, stream>>>(
            Ct, X, qt, nullptr, Gt, B_DIM, A_DIM, A_DIM);
        softmax_kernel<<<B_DIM, 256, 0, stream>>>(Gt, qt, Ct, num, denom);
        gemm_dot_kernel<<<dim3(A_DIM / 128, B_DIM / 128), 256, 0, stream>>>(Gt, X, denom);
        dupdate_kernel<<<B_DIM, 256, 0, stream>>>(Ct, Gt, num, denom);
    }

    // recon: out[b,:] = (Ct[b,:] @ an) * ynorm[b]   [B,768]
    gemm_k<false, 2><<<dim3(D_DIM / 128, B_DIM / 128), 256, 0, stream>>>(
        Ct, an, nullptr, ynorm, out, B_DIM, D_DIM, A_DIM);
}

// Round 4
// 11810.049 us; speedup vs baseline: 2.8074x; 2.8074x over previous
//
#include <hip/hip_runtime.h>
#include <hip/hip_bf16.h>
#include <math.h>

// Problem constants
#define A_DIM 1024      // NB_ATOMS
#define D_DIM 768       // 3*16*16
#define B_DIM 16384     // BATCH
#define TEMP_C 100.0f
#define EPS_C 1e-8f

// Layout: transposed vs reference: [B, A] row-major. X symmetric.
// grad^T[b,a] = (c_b . X[:,a]) - q[b,a], with q fused into the MFMA GEMM:
//   phase Q: acc += split(-y/||y||_1) @ split(an)^T   (K=768)
//   phase X: acc += split(c) @ split(X)               (K=1024)
// Nondiff: argmin + row reductions fused into the GEMM epilogue (no Gt buffer);
// the 1024 sparse (a, bstar[a]) entries are recomputed in fp32 by a tiny kernel.
// Diff: grad -> G; softmax -> sm in G, split(d)=split(sm-c) in Chi/Clo;
// denom = d.(X@d) via dot-MFMA-GEMM; update: c_new = sm - (1-lam)*d.
// c canonical as bf16 hi/lo pair (Chi/Clo). Workspace ~193 MiB.

typedef __attribute__((ext_vector_type(8))) short short8;
typedef __attribute__((ext_vector_type(4))) float f32x4;
#define MFMA16(a, b, c) __builtin_amdgcn_mfma_f32_16x16x32_bf16(a, b, c, 0, 0, 0)

typedef __attribute__((address_space(3))) unsigned char lds_byte;
typedef __attribute__((address_space(1))) const unsigned char g_byte;
__device__ __forceinline__ void async_copy16(const void* gptr, void* lptr) {
    __builtin_amdgcn_global_load_lds((g_byte*)gptr, (lds_byte*)lptr, 16, 0, 0);
}

// ---------------- small helpers ----------------

__device__ __forceinline__ float block_reduce_sum(float v, float* red) {
    int t = threadIdx.x;
    red[t] = v; __syncthreads();
    for (int off = 128; off > 0; off >>= 1) {
        if (t < off) red[t] += red[t + off];
        __syncthreads();
    }
    float r = red[0];
    __syncthreads();
    return r;
}

__device__ __forceinline__ float block_reduce_max(float v, float* red) {
    int t = threadIdx.x;
    red[t] = v; __syncthreads();
    for (int off = 128; off > 0; off >>= 1) {
        if (t < off) red[t] = fmaxf(red[t], red[t + off]);
        __syncthreads();
    }
    float r = red[0];
    __syncthreads();
    return r;
}

// monotone float->uint transform for ordered integer min
__device__ __forceinline__ unsigned int fkey(float v) {
    unsigned int u = __float_as_uint(v);
    return u ^ ((u & 0x80000000u) ? 0xFFFFFFFFu : 0x80000000u);
}

// bf16 round-to-nearest-even + two-term split
__device__ __forceinline__ unsigned short f2bf(float x) {
    unsigned int u = __float_as_uint(x);
    return (unsigned short)((u + 0x7FFFu + ((u >> 16) & 1u)) >> 16);
}
__device__ __forceinline__ float bf2f(unsigned short h) {
    return __uint_as_float(((unsigned int)h) << 16);
}
__device__ __forceinline__ void split2(float x, unsigned short& hi, unsigned short& lo) {
    hi = f2bf(x);
    lo = f2bf(x - bf2f(hi));
}

// ---------------- MFMA building blocks ----------------

// wave stages a 128x32 bf16 tile: 8 x (64 lanes x 16B), LDS layout row*32+col
__device__ __forceinline__ void stage_tile8(const unsigned short* gsrc, int stride, int k0,
                                            unsigned short* ltile, int lane) {
    int srow = lane >> 2;
    int scol = (lane & 3) * 8;
#pragma unroll
    for (int s = 0; s < 8; s++) {
        const unsigned short* src = gsrc + (size_t)(s * 16 + srow) * stride + k0 + scol;
        async_copy16(src, ltile + s * 512);
    }
}

// one K=32 step: 16 tile-pairs x 3 split products
__device__ __forceinline__ void mfma_k32(const unsigned short* lds, int wm, int wn, int lane,
                                         f32x4 acc[4][4]) {
    int frow = lane & 15, fk = (lane >> 4) * 8;
    short8 ah[4], al[4], bh[4], bl[4];
#pragma unroll
    for (int t = 0; t < 4; t++) {
        int ar = (wm * 64 + t * 16 + frow) * 32 + fk;
        ah[t] = *(const short8*)&lds[ar];
        al[t] = *(const short8*)&lds[4096 + ar];
        int br = (wn * 64 + t * 16 + frow) * 32 + fk;
        bh[t] = *(const short8*)&lds[8192 + br];
        bl[t] = *(const short8*)&lds[12288 + br];
    }
#pragma unroll
    for (int i = 0; i < 4; i++)
#pragma unroll
        for (int j = 0; j < 4; j++) {
            acc[i][j] = MFMA16(ah[i], bh[j], acc[i][j]);
            acc[i][j] = MFMA16(ah[i], bl[j], acc[i][j]);
            acc[i][j] = MFMA16(al[i], bh[j], acc[i][j]);
        }
}

// ---------------- setup kernels ----------------

__global__ __launch_bounds__(256) void ynorm_kernel(const float* __restrict__ y,
                                                    float* __restrict__ ynorm) {
    __shared__ float red[256];
    int b = blockIdx.x;
    const float* row = y + (size_t)b * D_DIM;
    float s = 0.f;
    for (int i = threadIdx.x; i < D_DIM; i += 256) s += fabsf(row[i]);
    float tot = block_reduce_sum(s, red);
    if (threadIdx.x == 0) ynorm[b] = tot;
}

// Ynh/Ynl = split(-y/ynorm)  [B,768]
__global__ __launch_bounds__(256) void yn_split_kernel(const float* __restrict__ y,
                                                       const float* __restrict__ ynorm,
                                                       unsigned short* __restrict__ Ynh,
                                                       unsigned short* __restrict__ Ynl) {
    int b = blockIdx.x;
    float inv = -1.f / ynorm[b];
    const float* row = y + (size_t)b * D_DIM;
    unsigned short* oh = Ynh + (size_t)b * D_DIM;
    unsigned short* ol = Ynl + (size_t)b * D_DIM;
    for (int i = threadIdx.x; i < D_DIM; i += 256) {
        unsigned short h, l;
        split2(row[i] * inv, h, l);
        oh[i] = h; ol[i] = l;
    }
}

// an = L1-normalized atoms (fp32) + bf16 splits  [A,768]
__global__ __launch_bounds__(256) void anorm_split_kernel(const float* __restrict__ atoms,
                                                          float* __restrict__ an,
                                                          unsigned short* __restrict__ Anh,
                                                          unsigned short* __restrict__ Anl) {
    __shared__ float red[256];
    int a = blockIdx.x;
    const float* row = atoms + (size_t)a * D_DIM;
    float s = 0.f;
    for (int i = threadIdx.x; i < D_DIM; i += 256) s += fabsf(row[i]);
    float tot = block_reduce_sum(s, red);
    float inv = 1.f / tot;
    for (int i = threadIdx.x; i < D_DIM; i += 256) {
        float v = row[i] * inv;
        an[(size_t)a * D_DIM + i] = v;
        unsigned short h, l;
        split2(v, h, l);
        Anh[(size_t)a * D_DIM + i] = h;
        Anl[(size_t)a * D_DIM + i] = l;
    }
}

// AnT[n,k] = an[k,n] splits  [768,1024]
__global__ __launch_bounds__(256) void atrans_split_kernel(const float* __restrict__ an,
                                                           unsigned short* __restrict__ AnTh,
                                                           unsigned short* __restrict__ AnTl) {
    int n = blockIdx.x;  // pixel
    for (int k = threadIdx.x; k < A_DIM; k += 256) {
        float v = an[(size_t)k * D_DIM + n];
        unsigned short h, l;
        split2(v, h, l);
        AnTh[(size_t)n * A_DIM + k] = h;
        AnTl[(size_t)n * A_DIM + k] = l;
    }
}

// generic fp32 -> hi/lo split
__global__ __launch_bounds__(256) void split_kernel(const float* __restrict__ src,
                                                    unsigned short* __restrict__ hi,
                                                    unsigned short* __restrict__ lo,
                                                    int n4) {
    int i = blockIdx.x * 256 + threadIdx.x;
    if (i < n4) {
        float4 v = ((const float4*)src)[i];
        ushort4 h, l;
        split2(v.x, h.x, l.x);
        split2(v.y, h.y, l.y);
        split2(v.z, h.z, l.z);
        split2(v.w, h.w, l.w);
        ((ushort4*)hi)[i] = h;
        ((ushort4*)lo)[i] = l;
    }
}

// c pair = split(1/1024)
__global__ __launch_bounds__(256) void fill_pair_kernel(unsigned short* __restrict__ Chi,
                                                        unsigned short* __restrict__ Clo,
                                                        size_t n4) {
    size_t i = (size_t)blockIdx.x * 256 + threadIdx.x;
    if (i < n4) {
        unsigned short h, l;
        split2(1.f / A_DIM, h, l);
        ((ushort4*)Chi)[i] = make_ushort4(h, h, h, h);
        ((ushort4*)Clo)[i] = make_ushort4(l, l, l, l);
    }
}

// fp32 vector GEMM, BT=true only (X = an @ an^T setup)
__global__ __launch_bounds__(256) void gemm_xt(const float* __restrict__ Aop,
                                               float* __restrict__ Cout,
                                               int M, int N, int K) {
    const int LDT = 132;
    __shared__ float As[16 * LDT];
    __shared__ float Bs[16 * LDT];
    int m0 = blockIdx.y * 128, n0 = blockIdx.x * 128;
    int tid = threadIdx.x;
    int tx = tid & 15, ty = tid >> 4;
    float acc[8][8];
#pragma unroll
    for (int i = 0; i < 8; i++)
#pragma unroll
        for (int j = 0; j < 8; j++) acc[i][j] = 0.f;
    for (int k0 = 0; k0 < K; k0 += 16) {
#pragma unroll
        for (int s = 0; s < 2; s++) {
            int idx = tid + s * 256;
            int row = idx >> 2, kq = (idx & 3) * 4;
            float4 v = *(const float4*)(Aop + (size_t)(m0 + row) * K + k0 + kq);
            As[(kq + 0) * LDT + row] = v.x;
            As[(kq + 1) * LDT + row] = v.y;
            As[(kq + 2) * LDT + row] = v.z;
            As[(kq + 3) * LDT + row] = v.w;
        }
#pragma unroll
        for (int s = 0; s < 2; s++) {
            int idx = tid + s * 256;
            int row = idx >> 2, kq = (idx & 3) * 4;
            float4 v = *(const float4*)(Aop + (size_t)(n0 + row) * K + k0 + kq);
            Bs[(kq + 0) * LDT + row] = v.x;
            Bs[(kq + 1) * LDT + row] = v.y;
            Bs[(kq + 2) * LDT + row] = v.z;
            Bs[(kq + 3) * LDT + row] = v.w;
        }
        __syncthreads();
#pragma unroll
        for (int kk = 0; kk < 16; kk++) {
            float a[8], b[8];
            *(float4*)(a)     = *(const float4*)(As + kk * LDT + ty * 8);
            *(float4*)(a + 4) = *(const float4*)(As + kk * LDT + ty * 8 + 4);
            *(float4*)(b)     = *(const float4*)(Bs + kk * LDT + tx * 8);
            *(float4*)(b + 4) = *(const float4*)(Bs + kk * LDT + tx * 8 + 4);
#pragma unroll
            for (int i = 0; i < 8; i++)
#pragma unroll
                for (int j = 0; j < 8; j++) acc[i][j] = fmaf(a[i], b[j], acc[i][j]);
        }
        __syncthreads();
    }
#pragma unroll
    for (int i = 0; i < 8; i++) {
        int row = m0 + ty * 8 + i;
#pragma unroll
        for (int j = 0; j < 8; j += 4) {
            int col = n0 + tx * 8 + j;
            float4 v = make_float4(acc[i][j], acc[i][j + 1], acc[i][j + 2], acc[i][j + 3]);
            *(float4*)(Cout + (size_t)row * N + col) = v;
        }
    }
}

// ---------------- fused grad MFMA GEMM ----------------
// MODE 0 (nondiff): epilogue does column argmin -> keys, row c.g -> num_cg,
//                   sum c.Xc -> scal[1]   (Xc = g - s1, s1 = -q snapshot)
// MODE 1 (diff):    epilogue writes g to G
template <int MODE>
__global__ __launch_bounds__(256) void fused_grad(const unsigned short* __restrict__ Chi,
                                                  const unsigned short* __restrict__ Clo,
                                                  const unsigned short* __restrict__ Xhi,
                                                  const unsigned short* __restrict__ Xlo,
                                                  const unsigned short* __restrict__ Ynh,
                                                  const unsigned short* __restrict__ Ynl,
                                                  const unsigned short* __restrict__ Anh,
                                                  const unsigned short* __restrict__ Anl,
                                                  unsigned long long* __restrict__ keys,
                                                  float* __restrict__ num_cg,
                                                  float* __restrict__ scal,
                                                  float* __restrict__ G) {
    __shared__ unsigned short lds[16384];
    __shared__ float red[256];
    int tid = threadIdx.x;
    int w = tid >> 6, lane = tid & 63;
    int wm = w >> 1, wn = w & 1;
    int m0 = blockIdx.y * 128, n0 = blockIdx.x * 128;

    f32x4 acc[4][4];
#pragma unroll
    for (int i = 0; i < 4; i++)
#pragma unroll
        for (int j = 0; j < 4; j++) acc[i][j] = f32x4{0.f, 0.f, 0.f, 0.f};

    // ---- phase Q: acc = -q  (K = 768) ----
    {
        const unsigned short* gsrc;
        if (w == 0) gsrc = Ynh + (size_t)m0 * D_DIM;
        else if (w == 1) gsrc = Ynl + (size_t)m0 * D_DIM;
        else if (w == 2) gsrc = Anh + (size_t)n0 * D_DIM;
        else gsrc = Anl + (size_t)n0 * D_DIM;
        unsigned short* ltile = lds + w * 4096;
        for (int k0 = 0; k0 < D_DIM; k0 += 32) {
            stage_tile8(gsrc, D_DIM, k0, ltile, lane);
            __syncthreads();
            mfma_k32(lds, wm, wn, lane, acc);
            __syncthreads();
        }
    }
    f32x4 s1[4][4];
    if (MODE == 0) {
#pragma unroll
        for (int i = 0; i < 4; i++)
#pragma unroll
            for (int j = 0; j < 4; j++) s1[i][j] = acc[i][j];
    }
    // ---- phase X: acc += c.X  (K = 1024) -> acc = g ----
    {
        const unsigned short* gsrc;
        if (w == 0) gsrc = Chi + (size_t)m0 * A_DIM;
        else if (w == 1) gsrc = Clo + (size_t)m0 * A_DIM;
        else if (w == 2) gsrc = Xhi + (size_t)n0 * A_DIM;
        else gsrc = Xlo + (size_t)n0 * A_DIM;
        unsigned short* ltile = lds + w * 4096;
        for (int k0 = 0; k0 < A_DIM; k0 += 32) {
            stage_tile8(gsrc, A_DIM, k0, ltile, lane);
            __syncthreads();
            mfma_k32(lds, wm, wn, lane, acc);
            __syncthreads();
        }
    }

    // C/D layout: col = lane&15, row = (lane>>4)*4 + reg  [m89-verified]
    int crow = (lane >> 4) * 4, ccol = lane & 15;

    if (MODE == 1) {
#pragma unroll
        for (int i = 0; i < 4; i++) {
            int gm = m0 + wm * 64 + i * 16 + crow;
#pragma unroll
            for (int j = 0; j < 4; j++) {
                int gn = n0 + wn * 64 + j * 16 + ccol;
#pragma unroll
                for (int r = 0; r < 4; r++)
                    G[(size_t)(gm + r) * A_DIM + gn] = acc[i][j][r];
            }
        }
        return;
    }

    // ---- MODE 0 epilogue ----
    // column argmin over this block's 128 rows, packed (fkey<<32)|row
#pragma unroll
    for (int j = 0; j < 4; j++) {
        unsigned long long best = ~0ULL;
#pragma unroll
        for (int i = 0; i < 4; i++)
#pragma unroll
            for (int r = 0; r < 4; r++) {
                int b = m0 + wm * 64 + i * 16 + crow + r;
                unsigned long long key =
                    ((unsigned long long)fkey(acc[i][j][r]) << 32) | (unsigned int)b;
                if (key < best) best = key;
            }
        // reduce across the 4 quads holding the same column
        unsigned long long o = __shfl_xor(best, 16);
        if (o < best) best = o;
        o = __shfl_xor(best, 32);
        if (o < best) best = o;
        if ((lane >> 4) == 0)
            atomicMin(&keys[n0 + wn * 64 + j * 16 + ccol], best);
    }

    // row partials: c.g -> num_cg[row]; sum_b c.Xc -> scal[1]
    float cxc_part = 0.f;
#pragma unroll
    for (int i = 0; i < 4; i++)
#pragma unroll
        for (int r = 0; r < 4; r++) {
            int gm = m0 + wm * 64 + i * 16 + crow + r;
            float pcg = 0.f, pcx = 0.f;
#pragma unroll
            for (int j = 0; j < 4; j++) {
                int gn = n0 + wn * 64 + j * 16 + ccol;
                size_t idx = (size_t)gm * A_DIM + gn;
                float c = bf2f(Chi[idx]) + bf2f(Clo[idx]);
                float g = acc[i][j][r];
                float xc = g - s1[i][j][r];
                pcg += c * g;
                pcx += c * xc;
            }
            for (int mm = 1; mm < 16; mm <<= 1) {
                pcg += __shfl_xor(pcg, mm, 16);
                pcx += __shfl_xor(pcx, mm, 16);
            }
            if (ccol == 0) {
                atomicAdd(&num_cg[gm], pcg);
                cxc_part += pcx;
            }
        }
    float tot = block_reduce_sum(cxc_part, red);
    if (tid == 0) atomicAdd(&scal[1], tot);
}

// dot-GEMM: scal[3] += sum( (d @ X) .* d ), d = recon(Chi,Clo)
__global__ __launch_bounds__(256) void mfma_dot(const unsigned short* __restrict__ Chi,
                                                const unsigned short* __restrict__ Clo,
                                                const unsigned short* __restrict__ Xhi,
                                                const unsigned short* __restrict__ Xlo,
                                                float* __restrict__ scal) {
    __shared__ unsigned short lds[16384];
    __shared__ float red[256];
    int tid = threadIdx.x;
    int w = tid >> 6, lane = tid & 63;
    int wm = w >> 1, wn = w & 1;
    int m0 = blockIdx.y * 128, n0 = blockIdx.x * 128;

    f32x4 acc[4][4];
#pragma unroll
    for (int i = 0; i < 4; i++)
#pragma unroll
        for (int j = 0; j < 4; j++) acc[i][j] = f32x4{0.f, 0.f, 0.f, 0.f};

    const unsigned short* gsrc;
    if (w == 0) gsrc = Chi + (size_t)m0 * A_DIM;
    else if (w == 1) gsrc = Clo + (size_t)m0 * A_DIM;
    else if (w == 2) gsrc = Xhi + (size_t)n0 * A_DIM;
    else gsrc = Xlo + (size_t)n0 * A_DIM;
    unsigned short* ltile = lds + w * 4096;
    for (int k0 = 0; k0 < A_DIM; k0 += 32) {
        stage_tile8(gsrc, A_DIM, k0, ltile, lane);
        __syncthreads();
        mfma_k32(lds, wm, wn, lane, acc);
        __syncthreads();
    }

    int crow = (lane >> 4) * 4, ccol = lane & 15;
    float part = 0.f;
#pragma unroll
    for (int i = 0; i < 4; i++) {
        int gm = m0 + wm * 64 + i * 16 + crow;
#pragma unroll
        for (int j = 0; j < 4; j++) {
            int gn = n0 + wn * 64 + j * 16 + ccol;
#pragma unroll
            for (int r = 0; r < 4; r++) {
                size_t idx = (size_t)(gm + r) * A_DIM + gn;
                float d = bf2f(Chi[idx]) + bf2f(Clo[idx]);
                part += acc[i][j][r] * d;
            }
        }
    }
    float tot = block_reduce_sum(part, red);
    if (tid == 0) atomicAdd(&scal[3], tot);
}

// recon: out[b, n] = (c_b . anT[:,n]) * ynorm[b]   [B,768]
__global__ __launch_bounds__(256) void mfma_recon(const unsigned short* __restrict__ Chi,
                                                  const unsigned short* __restrict__ Clo,
                                                  const unsigned short* __restrict__ AnTh,
                                                  const unsigned short* __restrict__ AnTl,
                                                  const float* __restrict__ ynorm,
                                                  float* __restrict__ out) {
    __shared__ unsigned short lds[16384];
    int tid = threadIdx.x;
    int w = tid >> 6, lane = tid & 63;
    int wm = w >> 1, wn = w & 1;
    int m0 = blockIdx.y * 128, n0 = blockIdx.x * 128;

    f32x4 acc[4][4];
#pragma unroll
    for (int i = 0; i < 4; i++)
#pragma unroll
        for (int j = 0; j < 4; j++) acc[i][j] = f32x4{0.f, 0.f, 0.f, 0.f};

    const unsigned short* gsrc;
    if (w == 0) gsrc = Chi + (size_t)m0 * A_DIM;
    else if (w == 1) gsrc = Clo + (size_t)m0 * A_DIM;
    else if (w == 2) gsrc = AnTh + (size_t)n0 * A_DIM;
    else gsrc = AnTl + (size_t)n0 * A_DIM;
    unsigned short* ltile = lds + w * 4096;
    for (int k0 = 0; k0 < A_DIM; k0 += 32) {
        stage_tile8(gsrc, A_DIM, k0, ltile, lane);
        __syncthreads();
        mfma_k32(lds, wm, wn, lane, acc);
        __syncthreads();
    }

    int crow = (lane >> 4) * 4, ccol = lane & 15;
#pragma unroll
    for (int i = 0; i < 4; i++) {
        int gm = m0 + wm * 64 + i * 16 + crow;
#pragma unroll
        for (int j = 0; j < 4; j++) {
            int gn = n0 + wn * 64 + j * 16 + ccol;
#pragma unroll
            for (int r = 0; r < 4; r++)
                out[(size_t)(gm + r) * D_DIM + gn] = acc[i][j][r] * ynorm[gm + r];
        }
    }
}

// ---------------- per-iteration kernels ----------------

// zero keys / num_cg / num_amg / scal
__global__ __launch_bounds__(256) void init_kernel(unsigned long long* __restrict__ keys,
                                                   float* __restrict__ num_cg,
                                                   float* __restrict__ num_amg,
                                                   float* __restrict__ scal) {
    int i = blockIdx.x * 256 + threadIdx.x;
    num_cg[i] = 0.f;
    num_amg[i] = 0.f;
    if (i < A_DIM) keys[i] = ~0ULL;
    if (i < 4) scal[i] = 0.f;
}

__global__ __launch_bounds__(256) void extract_kernel(const unsigned long long* __restrict__ keys,
                                                      int* __restrict__ bstar) {
    int t = blockIdx.x * 256 + threadIdx.x;
    if (t < A_DIM) bstar[t] = (int)(unsigned int)(keys[t] & 0xFFFFFFFFULL);
}

// scal[0] += sum over pairs (a,a') with bstar[a]==bstar[a'] of X[a,a']
__global__ __launch_bounds__(256) void pairs_kernel(const float* __restrict__ X,
                                                    const int* __restrict__ bstar,
                                                    float* __restrict__ scal) {
    __shared__ float red[256];
    int a = blockIdx.x;
    int ba = bstar[a];
    const float* xr = X + (size_t)a * A_DIM;
    float s = 0.f;
    for (int i = threadIdx.x; i < A_DIM; i += 256)
        if (bstar[i] == ba) s += xr[i];
    float tot = block_reduce_sum(s, red);
    if (threadIdx.x == 0) atomicAdd(&scal[0], tot);
}

// fp32 recompute of Xc and g at the 1024 sparse (a, bstar[a]) entries:
//   scal[2] += Xc[bstar[a], a] ; num_amg[bstar[a]] += g[bstar[a], a]
__global__ __launch_bounds__(256) void sparse_kernel(const float* __restrict__ X,
                                                     const unsigned short* __restrict__ Chi,
                                                     const unsigned short* __restrict__ Clo,
                                                     const float* __restrict__ an,
                                                     const float* __restrict__ y,
                                                     const float* __restrict__ ynorm,
                                                     const int* __restrict__ bstar,
                                                     float* __restrict__ num_amg,
                                                     float* __restrict__ scal) {
    __shared__ float red[256];
    int a = blockIdx.x;
    int b = bstar[a];
    const float* xr = X + (size_t)a * A_DIM;
    const unsigned short* ch = Chi + (size_t)b * A_DIM;
    const unsigned short* cl = Clo + (size_t)b * A_DIM;
    float xs = 0.f;
    for (int k = threadIdx.x; k < A_DIM; k += 256)
        xs += xr[k] * (bf2f(ch[k]) + bf2f(cl[k]));
    float xc = block_reduce_sum(xs, red);
    const float* ar = an + (size_t)a * D_DIM;
    const float* yr = y + (size_t)b * D_DIM;
    float qs = 0.f;
    for (int k = threadIdx.x; k < D_DIM; k += 256) qs += ar[k] * yr[k];
    float qv = block_reduce_sum(qs, red) / ynorm[b];
    if (threadIdx.x == 0) {
        atomicAdd(&scal[2], xc);
        atomicAdd(&num_amg[b], xc - qv);
    }
}

// nondiff update: lam = clip((cg-amg)/(pairs + cXc - 2*amXc + eps)); c pair update
__global__ __launch_bounds__(256) void ndupdate_kernel(unsigned short* __restrict__ Chi,
                                                       unsigned short* __restrict__ Clo,
                                                       const int* __restrict__ bstar,
                                                       const float* __restrict__ num_cg,
                                                       const float* __restrict__ num_amg,
                                                       const float* __restrict__ scal) {
    int b = blockIdx.x;
    float den = scal[0] + scal[1] - 2.f * scal[2] + EPS_C;
    float lam = fminf(fmaxf((num_cg[b] - num_amg[b]) / den, 0.f), 1.f);
    int i = threadIdx.x;
    ushort4* h4 = (ushort4*)(Chi + (size_t)b * A_DIM);
    ushort4* l4 = (ushort4*)(Clo + (size_t)b * A_DIM);
    const int4* bs4 = (const int4*)bstar;
    ushort4 h = h4[i], l = l4[i];
    int4 bs = bs4[i];
    float c0 = bf2f(h.x) + bf2f(l.x);
    float c1 = bf2f(h.y) + bf2f(l.y);
    float c2 = bf2f(h.z) + bf2f(l.z);
    float c3 = bf2f(h.w) + bf2f(l.w);
    c0 += (((bs.x == b) ? 1.f : 0.f) - c0) * lam;
    c1 += (((bs.y == b) ? 1.f : 0.f) - c1) * lam;
    c2 += (((bs.z == b) ? 1.f : 0.f) - c2) * lam;
    c3 += (((bs.w == b) ? 1.f : 0.f) - c3) * lam;
    split2(c0, h.x, l.x);
    split2(c1, h.y, l.y);
    split2(c2, h.z, l.z);
    split2(c3, h.w, l.w);
    h4[i] = h; l4[i] = l;
}

// diff softmax: sm = softmax(-100*g) per row; num_cg[b] = (c-sm).g;
// G row <- sm ; Chi/Clo row <- split(sm - c)
__global__ __launch_bounds__(256) void softmax_kernel(float* __restrict__ G,
                                                      unsigned short* __restrict__ Chi,
                                                      unsigned short* __restrict__ Clo,
                                                      float* __restrict__ num_cg) {
    __shared__ float red[256];
    int b = blockIdx.x;
    int i = threadIdx.x;
    float4* g4 = (float4*)(G + (size_t)b * A_DIM);
    ushort4* h4 = (ushort4*)(Chi + (size_t)b * A_DIM);
    ushort4* l4 = (ushort4*)(Clo + (size_t)b * A_DIM);
    float4 g = g4[i];
    ushort4 h = h4[i], l = l4[i];
    float c0 = bf2f(h.x) + bf2f(l.x);
    float c1 = bf2f(h.y) + bf2f(l.y);
    float c2 = bf2f(h.z) + bf2f(l.z);
    float c3 = bf2f(h.w) + bf2f(l.w);
    float4 t = make_float4(-TEMP_C * g.x, -TEMP_C * g.y, -TEMP_C * g.z, -TEMP_C * g.w);
    float m = fmaxf(fmaxf(t.x, t.y), fmaxf(t.z, t.w));
    float M = block_reduce_max(m, red);
    float4 e = make_float4(expf(t.x - M), expf(t.y - M), expf(t.z - M), expf(t.w - M));
    float S = block_reduce_sum(e.x + e.y + e.z + e.w, red);
    float inv = 1.f / S;
    float4 sm = make_float4(e.x * inv, e.y * inv, e.z * inv, e.w * inv);
    float np = (c0 - sm.x) * g.x + (c1 - sm.y) * g.y + (c2 - sm.z) * g.z + (c3 - sm.w) * g.w;
    g4[i] = sm;
    split2(sm.x - c0, h.x, l.x);
    split2(sm.y - c1, h.y, l.y);
    split2(sm.z - c2, h.z, l.z);
    split2(sm.w - c3, h.w, l.w);
    h4[i] = h; l4[i] = l;
    float nt = block_reduce_sum(np, red);
    if (threadIdx.x == 0) num_cg[b] = nt;
}

// diff update: lam = clip(num/(scal[3]+eps)); c_new = sm - (1-lam)*d
__global__ __launch_bounds__(256) void dupdate_kernel(const float* __restrict__ G,
                                                      unsigned short* __restrict__ Chi,
                                                      unsigned short* __restrict__ Clo,
                                                      const float* __restrict__ num_cg,
                                                      const float* __restrict__ scal) {
    int b = blockIdx.x;
    float den = scal[3] + EPS_C;
    float lam = fminf(fmaxf(num_cg[b] / den, 0.f), 1.f);
    float om = 1.f - lam;
    int i = threadIdx.x;
    const float4* g4 = (const float4*)(G + (size_t)b * A_DIM);
    ushort4* h4 = (ushort4*)(Chi + (size_t)b * A_DIM);
    ushort4* l4 = (ushort4*)(Clo + (size_t)b * A_DIM);
    float4 sm = g4[i];
    ushort4 h = h4[i], l = l4[i];
    float d0 = bf2f(h.x) + bf2f(l.x);
    float d1 = bf2f(h.y) + bf2f(l.y);
    float d2 = bf2f(h.z) + bf2f(l.z);
    float d3 = bf2f(h.w) + bf2f(l.w);
    float c0 = sm.x - om * d0;
    float c1 = sm.y - om * d1;
    float c2 = sm.z - om * d2;
    float c3 = sm.w - om * d3;
    split2(c0, h.x, l.x);
    split2(c1, h.y, l.y);
    split2(c2, h.z, l.z);
    split2(c3, h.w, l.w);
    h4[i] = h; l4[i] = l;
}

// ---------------- host launch ----------------

extern "C" void kernel_launch(void* const* d_in, const int* in_sizes, int n_in,
                              void* d_out, int out_size, void* d_ws, size_t ws_size,
                              hipStream_t stream) {
    const float* y = (const float*)d_in[0];      // [B, 768]
    const float* atoms = (const float*)d_in[1];  // [A, 768]
    float* out = (float*)d_out;                  // [B, 768]

    char* ws = (char*)d_ws;
    size_t off = 0;
    auto alloc = [&](size_t bytes) -> void* {
        void* p = ws + off;
        off += (bytes + 255) & ~(size_t)255;
        return p;
    };
    const size_t BA = (size_t)B_DIM * A_DIM;
    unsigned short* Chi = (unsigned short*)alloc(BA * 2);            // 32 MiB
    unsigned short* Clo = (unsigned short*)alloc(BA * 2);            // 32 MiB
    float* G = (float*)alloc(BA * 4);                                // 64 MiB
    unsigned short* Ynh = (unsigned short*)alloc((size_t)B_DIM * D_DIM * 2);  // 24 MiB
    unsigned short* Ynl = (unsigned short*)alloc((size_t)B_DIM * D_DIM * 2);  // 24 MiB
    unsigned short* Anh = (unsigned short*)alloc((size_t)A_DIM * D_DIM * 2);  // 1.5 MiB
    unsigned short* Anl = (unsigned short*)alloc((size_t)A_DIM * D_DIM * 2);  // 1.5 MiB
    unsigned short* AnTh = (unsigned short*)alloc((size_t)D_DIM * A_DIM * 2); // 1.5 MiB
    unsigned short* AnTl = (unsigned short*)alloc((size_t)D_DIM * A_DIM * 2); // 1.5 MiB
    float* an = (float*)alloc((size_t)A_DIM * D_DIM * 4);            // 3 MiB
    float* X  = (float*)alloc((size_t)A_DIM * A_DIM * 4);            // 4 MiB
    unsigned short* Xhi = (unsigned short*)alloc((size_t)A_DIM * A_DIM * 2);  // 2 MiB
    unsigned short* Xlo = (unsigned short*)alloc((size_t)A_DIM * A_DIM * 2);  // 2 MiB
    float* ynorm = (float*)alloc(B_DIM * 4);
    float* num_cg = (float*)alloc(B_DIM * 4);
    float* num_amg = (float*)alloc(B_DIM * 4);
    unsigned long long* keys = (unsigned long long*)alloc(A_DIM * 8);
    int* bstar = (int*)alloc(A_DIM * 4);
    float* scal = (float*)alloc(256);
    (void)ws_size; (void)in_sizes; (void)n_in; (void)out_size;

    const dim3 ggrid(A_DIM / 128, B_DIM / 128);  // (8, 128)

    // setup
    ynorm_kernel<<<B_DIM, 256, 0, stream>>>(y, ynorm);
    yn_split_kernel<<<B_DIM, 256, 0, stream>>>(y, ynorm, Ynh, Ynl);
    anorm_split_kernel<<<A_DIM, 256, 0, stream>>>(atoms, an, Anh, Anl);
    atrans_split_kernel<<<D_DIM, 256, 0, stream>>>(an, AnTh, AnTl);
    gemm_xt<<<dim3(A_DIM / 128, A_DIM / 128), 256, 0, stream>>>(an, X, A_DIM, A_DIM, D_DIM);
    split_kernel<<<A_DIM * A_DIM / 4 / 256, 256, 0, stream>>>(X, Xhi, Xlo, A_DIM * A_DIM / 4);
    fill_pair_kernel<<<(int)(BA / 4 / 256), 256, 0, stream>>>(Chi, Clo, BA / 4);

    // 30 nondiff steps
    for (int it = 0; it < 30; it++) {
        init_kernel<<<B_DIM / 256, 256, 0, stream>>>(keys, num_cg, num_amg, scal);
        fused_grad<0><<<ggrid, 256, 0, stream>>>(Chi, Clo, Xhi, Xlo, Ynh, Ynl, Anh, Anl,
                                                 keys, num_cg, scal, nullptr);
        extract_kernel<<<4, 256, 0, stream>>>(keys, bstar);
        pairs_kernel<<<A_DIM, 256, 0, stream>>>(X, bstar, scal);
        sparse_kernel<<<A_DIM, 256, 0, stream>>>(X, Chi, Clo, an, y, ynorm, bstar,
                                                 num_amg, scal);
        ndupdate_kernel<<<B_DIM, 256, 0, stream>>>(Chi, Clo, bstar, num_cg, num_amg, scal);
    }

    // 10 diff steps
    for (int it = 0; it < 10; it++) {
        init_kernel<<<B_DIM / 256, 256, 0, stream>>>(keys, num_cg, num_amg, scal);
        fused_grad<1><<<ggrid, 256, 0, stream>>>(Chi, Clo, Xhi, Xlo, Ynh, Ynl, Anh, Anl,
                                                 keys, num_cg, scal, G);
        softmax_kernel<<<B_DIM, 256, 0, stream>>>(G, Chi, Clo, num_cg);
        mfma_dot<<<ggrid, 256, 0, stream>>>(Chi, Clo, Xhi, Xlo, scal);
        dupdate_kernel<<<B_DIM, 256, 0, stream>>>(G, Chi, Clo, num_cg, scal);
    }

    // recon: out[b,:] = (c_b @ an) * ynorm[b]
    mfma_recon<<<dim3(D_DIM / 128, B_DIM / 128), 256, 0, stream>>>(Chi, Clo, AnTh, AnTl,
                                                                   ynorm, out);
}

// Round 5
// 11609.860 us; speedup vs baseline: 2.8558x; 1.0172x over previous
//
#include <hip/hip_runtime.h>
#include <hip/hip_bf16.h>
#include <math.h>

// Problem constants
#define A_DIM 1024      // NB_ATOMS
#define D_DIM 768       // 3*16*16
#define B_DIM 16384     // BATCH
#define TEMP_C 100.0f
#define EPS_C 1e-8f

// Layout: transposed vs reference: [B, A] row-major. X symmetric.
// Round 5: qt (= (y @ an^T)/||y||_1, iteration-invariant) is precomputed ONCE
// in fp32; the per-iteration MFMA GEMM is single-phase (acc = c.X, K=1024)
// with epilogue g = acc - qt. This deletes 43% of MFMA work + the Yn traffic
// vs round 4.
// Workspace aliasing (196 MiB < 199 proven-good):
//   Gregion (64 MiB): setup = fp32 X (4 MiB) + an fp32 (3 MiB, @ +4MiB);
//                     nondiff = X/an still live (stats_kernel reads X);
//                     diff = G (grad/softmax scratch, clobbers X/an);
//                     post-diff = AnT bf16 splits for recon.

typedef __attribute__((ext_vector_type(8))) short short8;
typedef __attribute__((ext_vector_type(4))) float f32x4;
#define MFMA16(a, b, c) __builtin_amdgcn_mfma_f32_16x16x32_bf16(a, b, c, 0, 0, 0)

typedef __attribute__((address_space(3))) unsigned char lds_byte;
typedef __attribute__((address_space(1))) const unsigned char g_byte;
__device__ __forceinline__ void async_copy16(const void* gptr, void* lptr) {
    __builtin_amdgcn_global_load_lds((g_byte*)gptr, (lds_byte*)lptr, 16, 0, 0);
}

// ---------------- small helpers ----------------

__device__ __forceinline__ float block_reduce_sum(float v, float* red) {
    int t = threadIdx.x;
    red[t] = v; __syncthreads();
    for (int off = 128; off > 0; off >>= 1) {
        if (t < off) red[t] += red[t + off];
        __syncthreads();
    }
    float r = red[0];
    __syncthreads();
    return r;
}

__device__ __forceinline__ float block_reduce_max(float v, float* red) {
    int t = threadIdx.x;
    red[t] = v; __syncthreads();
    for (int off = 128; off > 0; off >>= 1) {
        if (t < off) red[t] = fmaxf(red[t], red[t + off]);
        __syncthreads();
    }
    float r = red[0];
    __syncthreads();
    return r;
}

// monotone float->uint transform for ordered integer min
__device__ __forceinline__ unsigned int fkey(float v) {
    unsigned int u = __float_as_uint(v);
    return u ^ ((u & 0x80000000u) ? 0xFFFFFFFFu : 0x80000000u);
}

// bf16 round-to-nearest-even + two-term split
__device__ __forceinline__ unsigned short f2bf(float x) {
    unsigned int u = __float_as_uint(x);
    return (unsigned short)((u + 0x7FFFu + ((u >> 16) & 1u)) >> 16);
}
__device__ __forceinline__ float bf2f(unsigned short h) {
    return __uint_as_float(((unsigned int)h) << 16);
}
__device__ __forceinline__ void split2(float x, unsigned short& hi, unsigned short& lo) {
    hi = f2bf(x);
    lo = f2bf(x - bf2f(hi));
}

// ---------------- MFMA building blocks ----------------

// wave stages a 128x32 bf16 tile: 8 x (64 lanes x 16B), LDS layout row*32+col
__device__ __forceinline__ void stage_tile8(const unsigned short* gsrc, int stride, int k0,
                                            unsigned short* ltile, int lane) {
    int srow = lane >> 2;
    int scol = (lane & 3) * 8;
#pragma unroll
    for (int s = 0; s < 8; s++) {
        const unsigned short* src = gsrc + (size_t)(s * 16 + srow) * stride + k0 + scol;
        async_copy16(src, ltile + s * 512);
    }
}

// one K=32 step: 16 tile-pairs x 3 split products
__device__ __forceinline__ void mfma_k32(const unsigned short* lds, int wm, int wn, int lane,
                                         f32x4 acc[4][4]) {
    int frow = lane & 15, fk = (lane >> 4) * 8;
    short8 ah[4], al[4], bh[4], bl[4];
#pragma unroll
    for (int t = 0; t < 4; t++) {
        int ar = (wm * 64 + t * 16 + frow) * 32 + fk;
        ah[t] = *(const short8*)&lds[ar];
        al[t] = *(const short8*)&lds[4096 + ar];
        int br = (wn * 64 + t * 16 + frow) * 32 + fk;
        bh[t] = *(const short8*)&lds[8192 + br];
        bl[t] = *(const short8*)&lds[12288 + br];
    }
#pragma unroll
    for (int i = 0; i < 4; i++)
#pragma unroll
        for (int j = 0; j < 4; j++) {
            acc[i][j] = MFMA16(ah[i], bh[j], acc[i][j]);
            acc[i][j] = MFMA16(ah[i], bl[j], acc[i][j]);
            acc[i][j] = MFMA16(al[i], bh[j], acc[i][j]);
        }
}

// ---------------- setup kernels ----------------

__global__ __launch_bounds__(256) void ynorm_kernel(const float* __restrict__ y,
                                                    float* __restrict__ ynorm) {
    __shared__ float red[256];
    int b = blockIdx.x;
    const float* row = y + (size_t)b * D_DIM;
    float s = 0.f;
    for (int i = threadIdx.x; i < D_DIM; i += 256) s += fabsf(row[i]);
    float tot = block_reduce_sum(s, red);
    if (threadIdx.x == 0) ynorm[b] = tot;
}

// an = atoms / L1(atoms) (fp32, into Gregion) + store L1 norms
__global__ __launch_bounds__(256) void anorm_kernel(const float* __restrict__ atoms,
                                                    float* __restrict__ an,
                                                    float* __restrict__ anrm) {
    __shared__ float red[256];
    int a = blockIdx.x;
    const float* row = atoms + (size_t)a * D_DIM;
    float s = 0.f;
    for (int i = threadIdx.x; i < D_DIM; i += 256) s += fabsf(row[i]);
    float tot = block_reduce_sum(s, red);
    float inv = 1.f / tot;
    float* orow = an + (size_t)a * D_DIM;
    for (int i = threadIdx.x; i < D_DIM; i += 256) orow[i] = row[i] * inv;
    if (threadIdx.x == 0) anrm[a] = tot;
}

// post-diff: AnT[n,k] = atoms[k,n]/anrm[k] splits, into Gregion
__global__ __launch_bounds__(256) void atrans_split_kernel(const float* __restrict__ atoms,
                                                           const float* __restrict__ anrm,
                                                           unsigned short* __restrict__ AnTh,
                                                           unsigned short* __restrict__ AnTl) {
    int n = blockIdx.x;  // pixel
    for (int k = threadIdx.x; k < A_DIM; k += 256) {
        float v = atoms[(size_t)k * D_DIM + n] / anrm[k];
        unsigned short h, l;
        split2(v, h, l);
        AnTh[(size_t)n * A_DIM + k] = h;
        AnTl[(size_t)n * A_DIM + k] = l;
    }
}

// generic fp32 -> hi/lo split
__global__ __launch_bounds__(256) void split_kernel(const float* __restrict__ src,
                                                    unsigned short* __restrict__ hi,
                                                    unsigned short* __restrict__ lo,
                                                    int n4) {
    int i = blockIdx.x * 256 + threadIdx.x;
    if (i < n4) {
        float4 v = ((const float4*)src)[i];
        ushort4 h, l;
        split2(v.x, h.x, l.x);
        split2(v.y, h.y, l.y);
        split2(v.z, h.z, l.z);
        split2(v.w, h.w, l.w);
        ((ushort4*)hi)[i] = h;
        ((ushort4*)lo)[i] = l;
    }
}

// c pair = split(1/1024)
__global__ __launch_bounds__(256) void fill_pair_kernel(unsigned short* __restrict__ Chi,
                                                        unsigned short* __restrict__ Clo,
                                                        size_t n4) {
    size_t i = (size_t)blockIdx.x * 256 + threadIdx.x;
    if (i < n4) {
        unsigned short h, l;
        split2(1.f / A_DIM, h, l);
        ((ushort4*)Chi)[i] = make_ushort4(h, h, h, h);
        ((ushort4*)Clo)[i] = make_ushort4(l, l, l, l);
    }
}

// fp32 vector GEMM, B transposed ([N,K] row-major), setup only.
// EPI 0: plain (X = an@an^T). EPI 3: /rscale[row] (qt = y@an^T / ynorm).
template <int EPI>
__global__ __launch_bounds__(256) void gemm_bt(const float* __restrict__ Aop,
                                               const float* __restrict__ Bop,
                                               const float* __restrict__ rscale,
                                               float* __restrict__ Cout,
                                               int N, int K) {
    const int LDT = 132;
    __shared__ float As[16 * LDT];
    __shared__ float Bs[16 * LDT];
    int m0 = blockIdx.y * 128, n0 = blockIdx.x * 128;
    int tid = threadIdx.x;
    int tx = tid & 15, ty = tid >> 4;
    float acc[8][8];
#pragma unroll
    for (int i = 0; i < 8; i++)
#pragma unroll
        for (int j = 0; j < 8; j++) acc[i][j] = 0.f;
    for (int k0 = 0; k0 < K; k0 += 16) {
#pragma unroll
        for (int s = 0; s < 2; s++) {
            int idx = tid + s * 256;
            int row = idx >> 2, kq = (idx & 3) * 4;
            float4 v = *(const float4*)(Aop + (size_t)(m0 + row) * K + k0 + kq);
            As[(kq + 0) * LDT + row] = v.x;
            As[(kq + 1) * LDT + row] = v.y;
            As[(kq + 2) * LDT + row] = v.z;
            As[(kq + 3) * LDT + row] = v.w;
        }
#pragma unroll
        for (int s = 0; s < 2; s++) {
            int idx = tid + s * 256;
            int row = idx >> 2, kq = (idx & 3) * 4;
            float4 v = *(const float4*)(Bop + (size_t)(n0 + row) * K + k0 + kq);
            Bs[(kq + 0) * LDT + row] = v.x;
            Bs[(kq + 1) * LDT + row] = v.y;
            Bs[(kq + 2) * LDT + row] = v.z;
            Bs[(kq + 3) * LDT + row] = v.w;
        }
        __syncthreads();
#pragma unroll
        for (int kk = 0; kk < 16; kk++) {
            float a[8], b[8];
            *(float4*)(a)     = *(const float4*)(As + kk * LDT + ty * 8);
            *(float4*)(a + 4) = *(const float4*)(As + kk * LDT + ty * 8 + 4);
            *(float4*)(b)     = *(const float4*)(Bs + kk * LDT + tx * 8);
            *(float4*)(b + 4) = *(const float4*)(Bs + kk * LDT + tx * 8 + 4);
#pragma unroll
            for (int i = 0; i < 8; i++)
#pragma unroll
                for (int j = 0; j < 8; j++) acc[i][j] = fmaf(a[i], b[j], acc[i][j]);
        }
        __syncthreads();
    }
#pragma unroll
    for (int i = 0; i < 8; i++) {
        int row = m0 + ty * 8 + i;
        float rs = (EPI == 3) ? (1.f / rscale[row]) : 1.f;
#pragma unroll
        for (int j = 0; j < 8; j += 4) {
            int col = n0 + tx * 8 + j;
            float4 v = make_float4(acc[i][j] * rs, acc[i][j + 1] * rs,
                                   acc[i][j + 2] * rs, acc[i][j + 3] * rs);
            *(float4*)(Cout + (size_t)row * N + col) = v;
        }
    }
}

// ---------------- per-iteration MFMA GEMM ----------------
// acc = split(c) @ split(X)  (K=1024), single phase. g = acc - qt.
// MODE 0 (nondiff): epilogue does column argmin(g) -> keys, row c.g -> num_cg,
//                   sum c.(Xc) -> scal[1]  (Xc = acc).
// MODE 1 (diff):    epilogue writes g to G.
template <int MODE>
__global__ __launch_bounds__(256) void fused_grad(const unsigned short* __restrict__ Chi,
                                                  const unsigned short* __restrict__ Clo,
                                                  const unsigned short* __restrict__ Xhi,
                                                  const unsigned short* __restrict__ Xlo,
                                                  const float* __restrict__ qt,
                                                  unsigned long long* __restrict__ keys,
                                                  float* __restrict__ num_cg,
                                                  float* __restrict__ scal,
                                                  float* __restrict__ G) {
    __shared__ unsigned short lds[16384];
    __shared__ float red[256];
    int tid = threadIdx.x;
    int w = tid >> 6, lane = tid & 63;
    int wm = w >> 1, wn = w & 1;
    int m0 = blockIdx.y * 128, n0 = blockIdx.x * 128;

    f32x4 acc[4][4];
#pragma unroll
    for (int i = 0; i < 4; i++)
#pragma unroll
        for (int j = 0; j < 4; j++) acc[i][j] = f32x4{0.f, 0.f, 0.f, 0.f};

    const unsigned short* gsrc;
    if (w == 0) gsrc = Chi + (size_t)m0 * A_DIM;
    else if (w == 1) gsrc = Clo + (size_t)m0 * A_DIM;
    else if (w == 2) gsrc = Xhi + (size_t)n0 * A_DIM;
    else gsrc = Xlo + (size_t)n0 * A_DIM;
    unsigned short* ltile = lds + w * 4096;
    for (int k0 = 0; k0 < A_DIM; k0 += 32) {
        stage_tile8(gsrc, A_DIM, k0, ltile, lane);
        __syncthreads();
        mfma_k32(lds, wm, wn, lane, acc);
        __syncthreads();
    }

    // C/D layout: col = lane&15, row = (lane>>4)*4 + reg  [m89-verified]
    int crow = (lane >> 4) * 4, ccol = lane & 15;

    if (MODE == 1) {
#pragma unroll
        for (int i = 0; i < 4; i++) {
            int gm = m0 + wm * 64 + i * 16 + crow;
#pragma unroll
            for (int j = 0; j < 4; j++) {
                int gn = n0 + wn * 64 + j * 16 + ccol;
#pragma unroll
                for (int r = 0; r < 4; r++) {
                    size_t idx = (size_t)(gm + r) * A_DIM + gn;
                    G[idx] = acc[i][j][r] - qt[idx];
                }
            }
        }
        return;
    }

    // ---- MODE 0 epilogue ----
    // pass 1: g = acc - qt in place; column argmin over this block's 128 rows
#pragma unroll
    for (int j = 0; j < 4; j++) {
        unsigned long long best = ~0ULL;
#pragma unroll
        for (int i = 0; i < 4; i++) {
            int gn = n0 + wn * 64 + j * 16 + ccol;
#pragma unroll
            for (int r = 0; r < 4; r++) {
                int b = m0 + wm * 64 + i * 16 + crow + r;
                float g = acc[i][j][r] - qt[(size_t)b * A_DIM + gn];
                acc[i][j][r] = g;
                unsigned long long key =
                    ((unsigned long long)fkey(g) << 32) | (unsigned int)b;
                if (key < best) best = key;
            }
        }
        unsigned long long o = __shfl_xor(best, 16);
        if (o < best) best = o;
        o = __shfl_xor(best, 32);
        if (o < best) best = o;
        if ((lane >> 4) == 0)
            atomicMin(&keys[n0 + wn * 64 + j * 16 + ccol], best);
    }

    // pass 2: row partials: c.g -> num_cg[row]; sum_b c.(Xc) -> scal[1]
    // (Xc = g + qt, re-read qt — L2-hot from pass 1)
    float cxc_part = 0.f;
#pragma unroll
    for (int i = 0; i < 4; i++)
#pragma unroll
        for (int r = 0; r < 4; r++) {
            int gm = m0 + wm * 64 + i * 16 + crow + r;
            float pcg = 0.f, pcx = 0.f;
#pragma unroll
            for (int j = 0; j < 4; j++) {
                int gn = n0 + wn * 64 + j * 16 + ccol;
                size_t idx = (size_t)gm * A_DIM + gn;
                float c = bf2f(Chi[idx]) + bf2f(Clo[idx]);
                float g = acc[i][j][r];
                float xc = g + qt[idx];
                pcg += c * g;
                pcx += c * xc;
            }
            for (int mm = 1; mm < 16; mm <<= 1) {
                pcg += __shfl_xor(pcg, mm, 16);
                pcx += __shfl_xor(pcx, mm, 16);
            }
            if (ccol == 0) {
                atomicAdd(&num_cg[gm], pcg);
                cxc_part += pcx;
            }
        }
    float tot = block_reduce_sum(cxc_part, red);
    if (tid == 0) atomicAdd(&scal[1], tot);
}

// dot-GEMM: scal[3] += sum( (d @ X) .* d ), d = recon(Chi,Clo)
__global__ __launch_bounds__(256) void mfma_dot(const unsigned short* __restrict__ Chi,
                                                const unsigned short* __restrict__ Clo,
                                                const unsigned short* __restrict__ Xhi,
                                                const unsigned short* __restrict__ Xlo,
                                                float* __restrict__ scal) {
    __shared__ unsigned short lds[16384];
    __shared__ float red[256];
    int tid = threadIdx.x;
    int w = tid >> 6, lane = tid & 63;
    int wm = w >> 1, wn = w & 1;
    int m0 = blockIdx.y * 128, n0 = blockIdx.x * 128;

    f32x4 acc[4][4];
#pragma unroll
    for (int i = 0; i < 4; i++)
#pragma unroll
        for (int j = 0; j < 4; j++) acc[i][j] = f32x4{0.f, 0.f, 0.f, 0.f};

    const unsigned short* gsrc;
    if (w == 0) gsrc = Chi + (size_t)m0 * A_DIM;
    else if (w == 1) gsrc = Clo + (size_t)m0 * A_DIM;
    else if (w == 2) gsrc = Xhi + (size_t)n0 * A_DIM;
    else gsrc = Xlo + (size_t)n0 * A_DIM;
    unsigned short* ltile = lds + w * 4096;
    for (int k0 = 0; k0 < A_DIM; k0 += 32) {
        stage_tile8(gsrc, A_DIM, k0, ltile, lane);
        __syncthreads();
        mfma_k32(lds, wm, wn, lane, acc);
        __syncthreads();
    }

    int crow = (lane >> 4) * 4, ccol = lane & 15;
    float part = 0.f;
#pragma unroll
    for (int i = 0; i < 4; i++) {
        int gm = m0 + wm * 64 + i * 16 + crow;
#pragma unroll
        for (int j = 0; j < 4; j++) {
            int gn = n0 + wn * 64 + j * 16 + ccol;
#pragma unroll
            for (int r = 0; r < 4; r++) {
                size_t idx = (size_t)(gm + r) * A_DIM + gn;
                float d = bf2f(Chi[idx]) + bf2f(Clo[idx]);
                part += acc[i][j][r] * d;
            }
        }
    }
    float tot = block_reduce_sum(part, red);
    if (tid == 0) atomicAdd(&scal[3], tot);
}

// recon: out[b, n] = (c_b . anT[:,n]) * ynorm[b]   [B,768]
__global__ __launch_bounds__(256) void mfma_recon(const unsigned short* __restrict__ Chi,
                                                  const unsigned short* __restrict__ Clo,
                                                  const unsigned short* __restrict__ AnTh,
                                                  const unsigned short* __restrict__ AnTl,
                                                  const float* __restrict__ ynorm,
                                                  float* __restrict__ out) {
    __shared__ unsigned short lds[16384];
    int tid = threadIdx.x;
    int w = tid >> 6, lane = tid & 63;
    int wm = w >> 1, wn = w & 1;
    int m0 = blockIdx.y * 128, n0 = blockIdx.x * 128;

    f32x4 acc[4][4];
#pragma unroll
    for (int i = 0; i < 4; i++)
#pragma unroll
        for (int j = 0; j < 4; j++) acc[i][j] = f32x4{0.f, 0.f, 0.f, 0.f};

    const unsigned short* gsrc;
    if (w == 0) gsrc = Chi + (size_t)m0 * A_DIM;
    else if (w == 1) gsrc = Clo + (size_t)m0 * A_DIM;
    else if (w == 2) gsrc = AnTh + (size_t)n0 * A_DIM;
    else gsrc = AnTl + (size_t)n0 * A_DIM;
    unsigned short* ltile = lds + w * 4096;
    for (int k0 = 0; k0 < A_DIM; k0 += 32) {
        stage_tile8(gsrc, A_DIM, k0, ltile, lane);
        __syncthreads();
        mfma_k32(lds, wm, wn, lane, acc);
        __syncthreads();
    }

    int crow = (lane >> 4) * 4, ccol = lane & 15;
#pragma unroll
    for (int i = 0; i < 4; i++) {
        int gm = m0 + wm * 64 + i * 16 + crow;
#pragma unroll
        for (int j = 0; j < 4; j++) {
            int gn = n0 + wn * 64 + j * 16 + ccol;
#pragma unroll
            for (int r = 0; r < 4; r++)
                out[(size_t)(gm + r) * D_DIM + gn] = acc[i][j][r] * ynorm[gm + r];
        }
    }
}

// ---------------- per-iteration small kernels ----------------

__global__ __launch_bounds__(256) void init_kernel(unsigned long long* __restrict__ keys,
                                                   float* __restrict__ num_cg,
                                                   float* __restrict__ num_amg,
                                                   float* __restrict__ scal) {
    int i = blockIdx.x * 256 + threadIdx.x;
    num_cg[i] = 0.f;
    num_amg[i] = 0.f;
    if (i < A_DIM) keys[i] = ~0ULL;
    if (i < 4) scal[i] = 0.f;
}

// merged extract+pairs+sparse. Block a:
//   ba = keys[a].low32; bstar[a] = ba
//   scal[0] += sum_{i: keys[i].low==ba} X[a,i]           (am^T X am term)
//   xc = X[a,:] . c[ba,:]  (fp32 X, exact)
//   scal[2] += xc ; num_amg[ba] += xc - qt[ba,a]
__global__ __launch_bounds__(256) void stats_kernel(const float* __restrict__ X,
                                                    const unsigned long long* __restrict__ keys,
                                                    const unsigned short* __restrict__ Chi,
                                                    const unsigned short* __restrict__ Clo,
                                                    const float* __restrict__ qt,
                                                    int* __restrict__ bstar,
                                                    float* __restrict__ num_amg,
                                                    float* __restrict__ scal) {
    __shared__ float red[256];
    int a = blockIdx.x;
    int ba = (int)(unsigned int)(keys[a] & 0xFFFFFFFFULL);
    const float* xr = X + (size_t)a * A_DIM;
    const unsigned short* ch = Chi + (size_t)ba * A_DIM;
    const unsigned short* cl = Clo + (size_t)ba * A_DIM;
    float ps = 0.f, xs = 0.f;
    for (int i = threadIdx.x; i < A_DIM; i += 256) {
        float xv = xr[i];
        if ((int)(unsigned int)(keys[i] & 0xFFFFFFFFULL) == ba) ps += xv;
        xs += xv * (bf2f(ch[i]) + bf2f(cl[i]));
    }
    float pt = block_reduce_sum(ps, red);
    float xc = block_reduce_sum(xs, red);
    if (threadIdx.x == 0) {
        bstar[a] = ba;
        atomicAdd(&scal[0], pt);
        atomicAdd(&scal[2], xc);
        atomicAdd(&num_amg[ba], xc - qt[(size_t)ba * A_DIM + a]);
    }
}

// nondiff update: lam = clip((cg-amg)/(pairs + cXc - 2*amXc + eps)); c pair update
__global__ __launch_bounds__(256) void ndupdate_kernel(unsigned short* __restrict__ Chi,
                                                       unsigned short* __restrict__ Clo,
                                                       const int* __restrict__ bstar,
                                                       const float* __restrict__ num_cg,
                                                       const float* __restrict__ num_amg,
                                                       const float* __restrict__ scal) {
    int b = blockIdx.x;
    float den = scal[0] + scal[1] - 2.f * scal[2] + EPS_C;
    float lam = fminf(fmaxf((num_cg[b] - num_amg[b]) / den, 0.f), 1.f);
    int i = threadIdx.x;
    ushort4* h4 = (ushort4*)(Chi + (size_t)b * A_DIM);
    ushort4* l4 = (ushort4*)(Clo + (size_t)b * A_DIM);
    const int4* bs4 = (const int4*)bstar;
    ushort4 h = h4[i], l = l4[i];
    int4 bs = bs4[i];
    float c0 = bf2f(h.x) + bf2f(l.x);
    float c1 = bf2f(h.y) + bf2f(l.y);
    float c2 = bf2f(h.z) + bf2f(l.z);
    float c3 = bf2f(h.w) + bf2f(l.w);
    c0 += (((bs.x == b) ? 1.f : 0.f) - c0) * lam;
    c1 += (((bs.y == b) ? 1.f : 0.f) - c1) * lam;
    c2 += (((bs.z == b) ? 1.f : 0.f) - c2) * lam;
    c3 += (((bs.w == b) ? 1.f : 0.f) - c3) * lam;
    split2(c0, h.x, l.x);
    split2(c1, h.y, l.y);
    split2(c2, h.z, l.z);
    split2(c3, h.w, l.w);
    h4[i] = h; l4[i] = l;
}

// diff softmax: sm = softmax(-100*g) per row; num_cg[b] = (c-sm).g;
// G row <- sm ; Chi/Clo row <- split(sm - c)
__global__ __launch_bounds__(256) void softmax_kernel(float* __restrict__ G,
                                                      unsigned short* __restrict__ Chi,
                                                      unsigned short* __restrict__ Clo,
                                                      float* __restrict__ num_cg) {
    __shared__ float red[256];
    int b = blockIdx.x;
    int i = threadIdx.x;
    float4* g4 = (float4*)(G + (size_t)b * A_DIM);
    ushort4* h4 = (ushort4*)(Chi + (size_t)b * A_DIM);
    ushort4* l4 = (ushort4*)(Clo + (size_t)b * A_DIM);
    float4 g = g4[i];
    ushort4 h = h4[i], l = l4[i];
    float c0 = bf2f(h.x) + bf2f(l.x);
    float c1 = bf2f(h.y) + bf2f(l.y);
    float c2 = bf2f(h.z) + bf2f(l.z);
    float c3 = bf2f(h.w) + bf2f(l.w);
    float4 t = make_float4(-TEMP_C * g.x, -TEMP_C * g.y, -TEMP_C * g.z, -TEMP_C * g.w);
    float m = fmaxf(fmaxf(t.x, t.y), fmaxf(t.z, t.w));
    float M = block_reduce_max(m, red);
    float4 e = make_float4(expf(t.x - M), expf(t.y - M), expf(t.z - M), expf(t.w - M));
    float S = block_reduce_sum(e.x + e.y + e.z + e.w, red);
    float inv = 1.f / S;
    float4 sm = make_float4(e.x * inv, e.y * inv, e.z * inv, e.w * inv);
    float np = (c0 - sm.x) * g.x + (c1 - sm.y) * g.y + (c2 - sm.z) * g.z + (c3 - sm.w) * g.w;
    g4[i] = sm;
    split2(sm.x - c0, h.x, l.x);
    split2(sm.y - c1, h.y, l.y);
    split2(sm.z - c2, h.z, l.z);
    split2(sm.w - c3, h.w, l.w);
    h4[i] = h; l4[i] = l;
    float nt = block_reduce_sum(np, red);
    if (threadIdx.x == 0) num_cg[b] = nt;
}

// diff update: lam = clip(num/(scal[3]+eps)); c_new = sm - (1-lam)*d
__global__ __launch_bounds__(256) void dupdate_kernel(const float* __restrict__ G,
                                                      unsigned short* __restrict__ Chi,
                                                      unsigned short* __restrict__ Clo,
                                                      const float* __restrict__ num_cg,
                                                      const float* __restrict__ scal) {
    int b = blockIdx.x;
    float den = scal[3] + EPS_C;
    float lam = fminf(fmaxf(num_cg[b] / den, 0.f), 1.f);
    float om = 1.f - lam;
    int i = threadIdx.x;
    const float4* g4 = (const float4*)(G + (size_t)b * A_DIM);
    ushort4* h4 = (ushort4*)(Chi + (size_t)b * A_DIM);
    ushort4* l4 = (ushort4*)(Clo + (size_t)b * A_DIM);
    float4 sm = g4[i];
    ushort4 h = h4[i], l = l4[i];
    float d0 = bf2f(h.x) + bf2f(l.x);
    float d1 = bf2f(h.y) + bf2f(l.y);
    float d2 = bf2f(h.z) + bf2f(l.z);
    float d3 = bf2f(h.w) + bf2f(l.w);
    float c0 = sm.x - om * d0;
    float c1 = sm.y - om * d1;
    float c2 = sm.z - om * d2;
    float c3 = sm.w - om * d3;
    split2(c0, h.x, l.x);
    split2(c1, h.y, l.y);
    split2(c2, h.z, l.z);
    split2(c3, h.w, l.w);
    h4[i] = h; l4[i] = l;
}

// ---------------- host launch ----------------

extern "C" void kernel_launch(void* const* d_in, const int* in_sizes, int n_in,
                              void* d_out, int out_size, void* d_ws, size_t ws_size,
                              hipStream_t stream) {
    const float* y = (const float*)d_in[0];      // [B, 768]
    const float* atoms = (const float*)d_in[1];  // [A, 768]
    float* out = (float*)d_out;                  // [B, 768]

    char* ws = (char*)d_ws;
    size_t off = 0;
    auto alloc = [&](size_t bytes) -> void* {
        void* p = ws + off;
        off += (bytes + 255) & ~(size_t)255;
        return p;
    };
    const size_t BA = (size_t)B_DIM * A_DIM;
    unsigned short* Chi = (unsigned short*)alloc(BA * 2);            // 32 MiB
    unsigned short* Clo = (unsigned short*)alloc(BA * 2);            // 32 MiB
    float* Greg = (float*)alloc(BA * 4);                             // 64 MiB (aliased)
    float* qt = (float*)alloc(BA * 4);                               // 64 MiB
    unsigned short* Xhi = (unsigned short*)alloc((size_t)A_DIM * A_DIM * 2);  // 2 MiB
    unsigned short* Xlo = (unsigned short*)alloc((size_t)A_DIM * A_DIM * 2);  // 2 MiB
    float* ynorm = (float*)alloc(B_DIM * 4);
    float* anrm  = (float*)alloc(A_DIM * 4);
    float* num_cg = (float*)alloc(B_DIM * 4);
    float* num_amg = (float*)alloc(B_DIM * 4);
    unsigned long long* keys = (unsigned long long*)alloc(A_DIM * 8);
    int* bstar = (int*)alloc(A_DIM * 4);
    float* scal = (float*)alloc(256);
    (void)ws_size; (void)in_sizes; (void)n_in; (void)out_size;
    // Gregion aliases:
    float* X  = Greg;                                   // fp32 X, 4 MiB (setup+nondiff)
    float* an = Greg + (size_t)A_DIM * A_DIM;           // an fp32, 3 MiB (setup only)
    float* G  = Greg;                                   // diff-phase grad/softmax scratch
    unsigned short* AnTh = (unsigned short*)Greg;                 // post-diff, 1.5 MiB
    unsigned short* AnTl = (unsigned short*)Greg + (size_t)D_DIM * A_DIM;

    const dim3 ggrid(A_DIM / 128, B_DIM / 128);  // (8, 128)

    // ---- setup ----
    ynorm_kernel<<<B_DIM, 256, 0, stream>>>(y, ynorm);
    anorm_kernel<<<A_DIM, 256, 0, stream>>>(atoms, an, anrm);
    // X = an @ an^T (fp32, into Gregion)
    gemm_bt<0><<<dim3(A_DIM / 128, A_DIM / 128), 256, 0, stream>>>(
        an, an, nullptr, X, A_DIM, D_DIM);
    split_kernel<<<A_DIM * A_DIM / 4 / 256, 256, 0, stream>>>(X, Xhi, Xlo, A_DIM * A_DIM / 4);
    // qt = (y @ an^T) / ynorm[row]  (fp32, once)
    gemm_bt<3><<<dim3(A_DIM / 128, B_DIM / 128), 256, 0, stream>>>(
        y, an, ynorm, qt, A_DIM, D_DIM);
    fill_pair_kernel<<<(int)(BA / 4 / 256), 256, 0, stream>>>(Chi, Clo, BA / 4);

    // ---- 30 nondiff steps ----
    for (int it = 0; it < 30; it++) {
        init_kernel<<<B_DIM / 256, 256, 0, stream>>>(keys, num_cg, num_amg, scal);
        fused_grad<0><<<ggrid, 256, 0, stream>>>(Chi, Clo, Xhi, Xlo, qt,
                                                 keys, num_cg, scal, nullptr);
        stats_kernel<<<A_DIM, 256, 0, stream>>>(X, keys, Chi, Clo, qt,
                                                bstar, num_amg, scal);
        ndupdate_kernel<<<B_DIM, 256, 0, stream>>>(Chi, Clo, bstar, num_cg, num_amg, scal);
    }

    // ---- 10 diff steps (G clobbers X/an — both dead now) ----
    for (int it = 0; it < 10; it++) {
        init_kernel<<<B_DIM / 256, 256, 0, stream>>>(keys, num_cg, num_amg, scal);
        fused_grad<1><<<ggrid, 256, 0, stream>>>(Chi, Clo, Xhi, Xlo, qt,
                                                 keys, num_cg, scal, G);
        softmax_kernel<<<B_DIM, 256, 0, stream>>>(G, Chi, Clo, num_cg);
        mfma_dot<<<ggrid, 256, 0, stream>>>(Chi, Clo, Xhi, Xlo, scal);
        dupdate_kernel<<<B_DIM, 256, 0, stream>>>(G, Chi, Clo, num_cg, scal);
    }

    // ---- recon (AnT built into Gregion after G's last use) ----
    atrans_split_kernel<<<D_DIM, 256, 0, stream>>>(atoms, anrm, AnTh, AnTl);
    mfma_recon<<<dim3(D_DIM / 128, B_DIM / 128), 256, 0, stream>>>(Chi, Clo, AnTh, AnTl,
                                                                   ynorm, out);
}